// Round 10
// baseline (4470.871 us; speedup 1.0000x reference)
//
#include <hip/hip_runtime.h>

typedef short short8 __attribute__((ext_vector_type(8)));
typedef float f32x4 __attribute__((ext_vector_type(4)));

#define NWIN 2304
#define SMEM_BYTES 81920

static __device__ __forceinline__ unsigned short f2bf(float f) {
  unsigned int u = __float_as_uint(f);
  u += 0x7FFFu + ((u >> 16) & 1u);   // RNE
  return (unsigned short)(u >> 16);
}
static __device__ __forceinline__ float bf2f(unsigned short s) {
  return __uint_as_float(((unsigned int)s) << 16);
}
static __device__ __forceinline__ f32x4 mfma16(short8 a, short8 b, f32x4 c) {
  return __builtin_amdgcn_mfma_f32_16x16x32_bf16(a, b, c, 0, 0, 0);
}
static __device__ __forceinline__ short8 lds8(const unsigned short* p) {
  return *reinterpret_cast<const short8*>(p);
}
// XOR swizzles: 16B granule, spread by low row bits
static __device__ __forceinline__ int swzT(int r, int c) {   // [64][512]
  return r * 512 + ((((c >> 3) ^ (r & 7)) << 3) | (c & 7));
}
static __device__ __forceinline__ int swz128(int r, int c) { // [64][128]
  return r * 128 + ((((c >> 3) ^ (r & 7)) << 3) | (c & 7));
}
static __device__ __forceinline__ int swzV(int r, int c) {   // [128][64]
  return r * 64 + ((((c >> 3) ^ (r & 7)) << 3) | (c & 7));
}

// ---- weight prep: in[K][N] f32  ->  out[N][K] bf16 ----
__global__ void transpose_cvt_kernel(const float* __restrict__ in,
                                     unsigned short* __restrict__ out,
                                     int K, int N) {
  __shared__ float tile[32][33];
  int bn = blockIdx.x * 32, bk = blockIdx.y * 32;
  int tx = threadIdx.x & 31, ty = threadIdx.x >> 5;  // 256 thr: 32 x 8
#pragma unroll
  for (int r = 0; r < 32; r += 8)
    tile[ty + r][tx] = in[(size_t)(bk + ty + r) * N + bn + tx];
  __syncthreads();
#pragma unroll
  for (int r = 0; r < 32; r += 8)
    out[(size_t)(bn + ty + r) * K + bk + tx] = f2bf(tile[tx][ty + r]);
}

__global__ __launch_bounds__(512, 4)
void swin_fused(const float* __restrict__ x,
                const unsigned short* __restrict__ WqkvT,  // [1536][512] bf16
                const float* __restrict__ bqkv,
                const unsigned short* __restrict__ WoT,    // [512][512]
                const float* __restrict__ bo,
                const float* __restrict__ g1, const float* __restrict__ beta1,
                const unsigned short* __restrict__ W1T,    // [512][512]
                const float* __restrict__ bf1,
                const unsigned short* __restrict__ W2T,    // [512][512]
                const float* __restrict__ bf2,
                const float* __restrict__ g2, const float* __restrict__ beta2,
                unsigned short* __restrict__ X,            // [2304][64][512] bf16 ws
                float* __restrict__ out) {
  extern __shared__ unsigned char smem[];
  unsigned short* sBig = (unsigned short*)smem;            // [64][512] swz: x gather / x1
  unsigned short* sQ   = (unsigned short*)smem;            // [64][128] swz: q->P->O (attn)
  unsigned short* sK   = (unsigned short*)(smem + 16384);  // [64][128] swz: k (attn)
  unsigned short* sVt  = (unsigned short*)(smem + 32768);  // [128][64] swz: V^T (attn)
  unsigned short* sU   = (unsigned short*)(smem + 65536);  // [64][128] swz: hidden (FFN)
  float* sSum  = (float*)(smem + 65536);                   // overlay sU (LN only)
  float* sSq   = (float*)(smem + 67584);
  float* sMean = (float*)(smem + 69632);
  float* sRstd = (float*)(smem + 69888);

  const int tid = threadIdx.x;
  const int wvid = tid >> 6, lane = tid & 63;
  const int l16 = lane & 15, lg = lane >> 4;

  // XCD swizzle (bijective: 2304 % 8 == 0)
  const int wid = (blockIdx.x & 7) * 288 + (blockIdx.x >> 3);
  const int b = wid / 144, rem = wid % 144;
  const int h0 = (rem / 12) * 8, w0 = (rem % 12) * 8;
  const float* xb = x + (size_t)b * 512 * 9216 + (size_t)h0 * 96 + w0;
  float* ob = out + (size_t)b * 512 * 9216 + (size_t)h0 * 96 + w0;
  unsigned short* Xw = X + (size_t)wid * 32768;

  // wave roles
  const int c2 = wvid * 16 + l16;   // qkv col within 128 (A) / hidden col (F1)
  const int hh = wvid >> 2;         // head within pair (S / PV)
  const int mt4 = wvid & 3;         // 16-row tile (S / PV)
  const int ycol0 = wvid * 64;      // wave's 64 C-cols (OP / LN / F2)

  // ---- Phase -1: gather window -> sBig (swz), flush to global X (token-major) ----
#pragma unroll
  for (int it = 0; it < 16; ++it) {
    int gid = it * 512 + tid;                 // gid = c*16 + hr*2 + wq
    int c = gid >> 4, hr = (gid >> 1) & 7, wq = gid & 1;
    float4 v = *reinterpret_cast<const float4*>(xb + (size_t)c * 9216 + hr * 96 + wq * 4);
    int tok = hr * 8 + wq * 4;
    sBig[swzT(tok + 0, c)] = f2bf(v.x);
    sBig[swzT(tok + 1, c)] = f2bf(v.y);
    sBig[swzT(tok + 2, c)] = f2bf(v.z);
    sBig[swzT(tok + 3, c)] = f2bf(v.w);
  }
  __syncthreads();
#pragma unroll
  for (int it = 0; it < 8; ++it) {
    int gid = it * 512 + tid;                 // gid = row*64 + granule
    int row = gid >> 6, c0 = (gid & 63) * 8;
    *reinterpret_cast<short8*>(Xw + row * 512 + c0) = lds8(sBig + swzT(row, c0));
  }
  __syncthreads();  // X visible via L2; sBig region now reusable as sQ/sK/sVt

  f32x4 Yacc[4][4] = {};  // persistent o-proj accumulator [row tile][col tile]

  for (int hp = 0; hp < 4; ++hp) {   // head pairs
    // ---- Phase A: q,k,v in 3 lean passes (wave: 64 rows x 16 cols; A from X) ----
#pragma unroll
    for (int pass = 0; pass < 3; ++pass) {
      const unsigned short* wp = WqkvT + ((size_t)pass * 512 + hp * 128 + c2) * 512;
      f32x4 acc[4] = {};
      short8 wb[2];
      wb[0] = *(const short8*)(wp + lg * 8);
      wb[1] = *(const short8*)(wp + 32 + lg * 8);
#pragma unroll
      for (int ks = 0; ks < 16; ++ks) {
        int ko = ks * 32 + lg * 8;
        short8 cw = wb[ks & 1];
        if (ks < 14) wb[ks & 1] = *(const short8*)(wp + (ks + 2) * 32 + lg * 8);
        short8 a0 = *(const short8*)(Xw + (l16) * 512 + ko);
        short8 a1 = *(const short8*)(Xw + (16 + l16) * 512 + ko);
        short8 a2 = *(const short8*)(Xw + (32 + l16) * 512 + ko);
        short8 a3 = *(const short8*)(Xw + (48 + l16) * 512 + ko);
        acc[0] = mfma16(a0, cw, acc[0]);
        acc[1] = mfma16(a1, cw, acc[1]);
        acc[2] = mfma16(a2, cw, acc[2]);
        acc[3] = mfma16(a3, cw, acc[3]);
      }
      float bv = bqkv[pass * 512 + hp * 128 + c2];
      if (pass == 0) {
#pragma unroll
        for (int mt = 0; mt < 4; ++mt) {
          int tok0 = mt * 16 + lg * 4;
#pragma unroll
          for (int r = 0; r < 4; ++r)
            sQ[swz128(tok0 + r, c2)] = f2bf((acc[mt][r] + bv) * 0.125f);
        }
      } else if (pass == 1) {
#pragma unroll
        for (int mt = 0; mt < 4; ++mt) {
          int tok0 = mt * 16 + lg * 4;
#pragma unroll
          for (int r = 0; r < 4; ++r)
            sK[swz128(tok0 + r, c2)] = f2bf(acc[mt][r] + bv);
        }
      } else {
#pragma unroll
        for (int mt = 0; mt < 4; ++mt) {
          int tok0 = mt * 16 + lg * 4;
          ushort4 pk;
          pk.x = f2bf(acc[mt][0] + bv);
          pk.y = f2bf(acc[mt][1] + bv);
          pk.z = f2bf(acc[mt][2] + bv);
          pk.w = f2bf(acc[mt][3] + bv);
          *reinterpret_cast<ushort4*>(sVt + swzV(c2, tok0)) = pk;
        }
      }
    }
    __syncthreads();

    // ---- Phase S: scores + wave-local softmax (head hh, rows mt4*16..) ----
    {
      f32x4 sc[4] = {};
#pragma unroll
      for (int ks = 0; ks < 2; ++ks) {
        int kb = hh * 64 + ks * 32 + lg * 8;
        short8 a  = lds8(sQ + swz128(mt4 * 16 + l16, kb));
        short8 b0 = lds8(sK + swz128(l16, kb));
        short8 b1 = lds8(sK + swz128(16 + l16, kb));
        short8 b2 = lds8(sK + swz128(32 + l16, kb));
        short8 b3 = lds8(sK + swz128(48 + l16, kb));
        sc[0] = mfma16(a, b0, sc[0]);
        sc[1] = mfma16(a, b1, sc[1]);
        sc[2] = mfma16(a, b2, sc[2]);
        sc[3] = mfma16(a, b3, sc[3]);
      }
#pragma unroll
      for (int r = 0; r < 4; ++r) {
        float m = fmaxf(fmaxf(sc[0][r], sc[1][r]), fmaxf(sc[2][r], sc[3][r]));
        m = fmaxf(m, __shfl_xor(m, 1));
        m = fmaxf(m, __shfl_xor(m, 2));
        m = fmaxf(m, __shfl_xor(m, 4));
        m = fmaxf(m, __shfl_xor(m, 8));
        float e0 = __expf(sc[0][r] - m), e1 = __expf(sc[1][r] - m);
        float e2 = __expf(sc[2][r] - m), e3 = __expf(sc[3][r] - m);
        float s = e0 + e1 + e2 + e3;
        s += __shfl_xor(s, 1);
        s += __shfl_xor(s, 2);
        s += __shfl_xor(s, 4);
        s += __shfl_xor(s, 8);
        float inv = 1.0f / s;
        int row = mt4 * 16 + lg * 4 + r;
        sQ[swz128(row, hh * 64 + l16)]      = f2bf(e0 * inv);  // P over q (own rows)
        sQ[swz128(row, hh * 64 + 16 + l16)] = f2bf(e1 * inv);
        sQ[swz128(row, hh * 64 + 32 + l16)] = f2bf(e2 * inv);
        sQ[swz128(row, hh * 64 + 48 + l16)] = f2bf(e3 * inv);
      }
    }
    // no barrier: P produced and consumed by same wave

    // ---- Phase PV: O = P @ V (write O over P, own rows) ----
    {
      f32x4 ov[4] = {};
#pragma unroll
      for (int ks = 0; ks < 2; ++ks) {
        int kb = ks * 32 + lg * 8;
        short8 a  = lds8(sQ + swz128(mt4 * 16 + l16, hh * 64 + kb));
        short8 b0 = lds8(sVt + swzV(hh * 64 + l16, kb));
        short8 b1 = lds8(sVt + swzV(hh * 64 + 16 + l16, kb));
        short8 b2 = lds8(sVt + swzV(hh * 64 + 32 + l16, kb));
        short8 b3 = lds8(sVt + swzV(hh * 64 + 48 + l16, kb));
        ov[0] = mfma16(a, b0, ov[0]);
        ov[1] = mfma16(a, b1, ov[1]);
        ov[2] = mfma16(a, b2, ov[2]);
        ov[3] = mfma16(a, b3, ov[3]);
      }
#pragma unroll
      for (int r = 0; r < 4; ++r) {
        int row = mt4 * 16 + lg * 4 + r;
        sQ[swz128(row, hh * 64 + l16)]      = f2bf(ov[0][r]);
        sQ[swz128(row, hh * 64 + 16 + l16)] = f2bf(ov[1][r]);
        sQ[swz128(row, hh * 64 + 32 + l16)] = f2bf(ov[2][r]);
        sQ[swz128(row, hh * 64 + 48 + l16)] = f2bf(ov[3][r]);
      }
    }
    __syncthreads();

    // ---- Phase OP: Yacc += O @ Wo[hp*128.., ycol0..+64] ----
    {
      const unsigned short* wo[4];
#pragma unroll
      for (int nt = 0; nt < 4; ++nt)
        wo[nt] = WoT + (size_t)(ycol0 + nt * 16 + l16) * 512 + hp * 128;
#pragma unroll
      for (int ks = 0; ks < 4; ++ks) {
        int ko = ks * 32 + lg * 8;
        short8 a0 = lds8(sQ + swz128(l16, ko));
        short8 a1 = lds8(sQ + swz128(16 + l16, ko));
        short8 a2 = lds8(sQ + swz128(32 + l16, ko));
        short8 a3 = lds8(sQ + swz128(48 + l16, ko));
#pragma unroll
        for (int nt = 0; nt < 4; ++nt) {
          short8 w = *(const short8*)(wo[nt] + ko);
          Yacc[0][nt] = mfma16(a0, w, Yacc[0][nt]);
          Yacc[1][nt] = mfma16(a1, w, Yacc[1][nt]);
          Yacc[2][nt] = mfma16(a2, w, Yacc[2][nt]);
          Yacc[3][nt] = mfma16(a3, w, Yacc[3][nt]);
        }
      }
    }
    __syncthreads();  // next hp rewrites sQ/sK/sVt
  }

  // ---- Residual 1 (x from global) + LayerNorm 1 -> x1 in sBig ----
  {
#pragma unroll
    for (int nt = 0; nt < 4; ++nt) {
      int col = ycol0 + nt * 16 + l16;
      float bv = bo[col];
      const float* xc = xb + (size_t)col * 9216;
#pragma unroll
      for (int mt = 0; mt < 4; ++mt) {
        int row0 = mt * 16 + lg * 4;
        float4 xv = *reinterpret_cast<const float4*>(xc + (row0 >> 3) * 96 + (row0 & 7));
        Yacc[mt][nt][0] += bv + xv.x;
        Yacc[mt][nt][1] += bv + xv.y;
        Yacc[mt][nt][2] += bv + xv.z;
        Yacc[mt][nt][3] += bv + xv.w;
      }
    }
#pragma unroll
    for (int mt = 0; mt < 4; ++mt) {
#pragma unroll
      for (int r = 0; r < 4; ++r) {
        float s = Yacc[mt][0][r] + Yacc[mt][1][r] + Yacc[mt][2][r] + Yacc[mt][3][r];
        float q = Yacc[mt][0][r] * Yacc[mt][0][r] + Yacc[mt][1][r] * Yacc[mt][1][r] +
                  Yacc[mt][2][r] * Yacc[mt][2][r] + Yacc[mt][3][r] * Yacc[mt][3][r];
        s += __shfl_xor(s, 1); s += __shfl_xor(s, 2);
        s += __shfl_xor(s, 4); s += __shfl_xor(s, 8);
        q += __shfl_xor(q, 1); q += __shfl_xor(q, 2);
        q += __shfl_xor(q, 4); q += __shfl_xor(q, 8);
        if (l16 == 0) {
          sSum[wvid * 64 + mt * 16 + lg * 4 + r] = s;
          sSq[wvid * 64 + mt * 16 + lg * 4 + r] = q;
        }
      }
    }
    __syncthreads();
    if (tid < 64) {
      float s = 0.f, q = 0.f;
#pragma unroll
      for (int w = 0; w < 8; ++w) { s += sSum[w * 64 + tid]; q += sSq[w * 64 + tid]; }
      float mean = s * (1.0f / 512.0f);
      float var = q * (1.0f / 512.0f) - mean * mean;
      sMean[tid] = mean;
      sRstd[tid] = rsqrtf(var + 1e-5f);
    }
    __syncthreads();
#pragma unroll
    for (int nt = 0; nt < 4; ++nt) {
      int col = ycol0 + nt * 16 + l16;
      float gv = g1[col], bv = beta1[col];
#pragma unroll
      for (int mt = 0; mt < 4; ++mt) {
        int row0 = mt * 16 + lg * 4;
#pragma unroll
        for (int r = 0; r < 4; ++r) {
          float xv = (Yacc[mt][nt][r] - sMean[row0 + r]) * sRstd[row0 + r] * gv + bv;
          sBig[swzT(row0 + r, col)] = f2bf(xv);
        }
      }
    }
  }
  __syncthreads();

  // ---- FFN: 4 hidden chunks of 128 (x1 from sBig; U in sU) ----
  f32x4 Facc[4][4] = {};
  for (int hc = 0; hc < 4; ++hc) {
    // F1: u = relu(x1 @ W1 chunk) (wave: 64 rows x 16 hidden cols)
    {
      const int hcol = hc * 128 + c2;
      const unsigned short* w1p = W1T + (size_t)hcol * 512;
      f32x4 u[4] = {};
      short8 wbuf[2];
      wbuf[0] = *(const short8*)(w1p + lg * 8);
      wbuf[1] = *(const short8*)(w1p + 32 + lg * 8);
#pragma unroll
      for (int ks = 0; ks < 16; ++ks) {
        int ko = ks * 32 + lg * 8;
        short8 cw = wbuf[ks & 1];
        if (ks < 14)
          wbuf[ks & 1] = *(const short8*)(w1p + (ks + 2) * 32 + lg * 8);
        short8 a0 = lds8(sBig + swzT(l16, ko));
        short8 a1 = lds8(sBig + swzT(16 + l16, ko));
        short8 a2 = lds8(sBig + swzT(32 + l16, ko));
        short8 a3 = lds8(sBig + swzT(48 + l16, ko));
        u[0] = mfma16(a0, cw, u[0]);
        u[1] = mfma16(a1, cw, u[1]);
        u[2] = mfma16(a2, cw, u[2]);
        u[3] = mfma16(a3, cw, u[3]);
      }
      float bv = bf1[hcol];
#pragma unroll
      for (int mt = 0; mt < 4; ++mt) {
        int tok0 = mt * 16 + lg * 4;
#pragma unroll
        for (int r = 0; r < 4; ++r)
          sU[swz128(tok0 + r, c2)] = f2bf(fmaxf(u[mt][r] + bv, 0.0f));
      }
    }
    __syncthreads();
    // F2: Facc += u @ W2[hc*128.., ycol0..+64]
    {
      const unsigned short* w2[4];
#pragma unroll
      for (int nt = 0; nt < 4; ++nt)
        w2[nt] = W2T + (size_t)(ycol0 + nt * 16 + l16) * 512 + hc * 128;
#pragma unroll
      for (int ks = 0; ks < 4; ++ks) {
        int ko = ks * 32 + lg * 8;
        short8 a0 = lds8(sU + swz128(l16, ko));
        short8 a1 = lds8(sU + swz128(16 + l16, ko));
        short8 a2 = lds8(sU + swz128(32 + l16, ko));
        short8 a3 = lds8(sU + swz128(48 + l16, ko));
#pragma unroll
        for (int nt = 0; nt < 4; ++nt) {
          short8 w = *(const short8*)(w2[nt] + ko);
          Facc[0][nt] = mfma16(a0, w, Facc[0][nt]);
          Facc[1][nt] = mfma16(a1, w, Facc[1][nt]);
          Facc[2][nt] = mfma16(a2, w, Facc[2][nt]);
          Facc[3][nt] = mfma16(a3, w, Facc[3][nt]);
        }
      }
    }
    __syncthreads();  // sU reused next chunk
  }

  // ---- Residual 2 (x1 from sBig) + LayerNorm 2 -> output ----
  {
#pragma unroll
    for (int nt = 0; nt < 4; ++nt) {
      int col = ycol0 + nt * 16 + l16;
      float bv = bf2[col];
#pragma unroll
      for (int mt = 0; mt < 4; ++mt) {
        int row0 = mt * 16 + lg * 4;
#pragma unroll
        for (int r = 0; r < 4; ++r)
          Facc[mt][nt][r] += bv + bf2f(sBig[swzT(row0 + r, col)]);
      }
    }
#pragma unroll
    for (int mt = 0; mt < 4; ++mt) {
#pragma unroll
      for (int r = 0; r < 4; ++r) {
        float s = Facc[mt][0][r] + Facc[mt][1][r] + Facc[mt][2][r] + Facc[mt][3][r];
        float q = Facc[mt][0][r] * Facc[mt][0][r] + Facc[mt][1][r] * Facc[mt][1][r] +
                  Facc[mt][2][r] * Facc[mt][2][r] + Facc[mt][3][r] * Facc[mt][3][r];
        s += __shfl_xor(s, 1); s += __shfl_xor(s, 2);
        s += __shfl_xor(s, 4); s += __shfl_xor(s, 8);
        q += __shfl_xor(q, 1); q += __shfl_xor(q, 2);
        q += __shfl_xor(q, 4); q += __shfl_xor(q, 8);
        if (l16 == 0) {
          sSum[wvid * 64 + mt * 16 + lg * 4 + r] = s;
          sSq[wvid * 64 + mt * 16 + lg * 4 + r] = q;
        }
      }
    }
    __syncthreads();
    if (tid < 64) {
      float s = 0.f, q = 0.f;
#pragma unroll
      for (int w = 0; w < 8; ++w) { s += sSum[w * 64 + tid]; q += sSq[w * 64 + tid]; }
      float mean = s * (1.0f / 512.0f);
      float var = q * (1.0f / 512.0f) - mean * mean;
      sMean[tid] = mean;
      sRstd[tid] = rsqrtf(var + 1e-5f);
    }
    __syncthreads();
#pragma unroll
    for (int nt = 0; nt < 4; ++nt) {
      int col = ycol0 + nt * 16 + l16;
      float gv = g2[col], bv = beta2[col];
      float* op = ob + (size_t)col * 9216;
#pragma unroll
      for (int mt = 0; mt < 4; ++mt) {
        int t0 = mt * 16 + lg * 4;
        float4 o4;
        o4.x = (Facc[mt][nt][0] - sMean[t0 + 0]) * sRstd[t0 + 0] * gv + bv;
        o4.y = (Facc[mt][nt][1] - sMean[t0 + 1]) * sRstd[t0 + 1] * gv + bv;
        o4.z = (Facc[mt][nt][2] - sMean[t0 + 2]) * sRstd[t0 + 2] * gv + bv;
        o4.w = (Facc[mt][nt][3] - sMean[t0 + 3]) * sRstd[t0 + 3] * gv + bv;
        *reinterpret_cast<float4*>(op + (t0 >> 3) * 96 + (t0 & 7)) = o4;
      }
    }
  }
}

extern "C" void kernel_launch(void* const* d_in, const int* in_sizes, int n_in,
                              void* d_out, int out_size, void* d_ws, size_t ws_size,
                              hipStream_t stream) {
  const float* x     = (const float*)d_in[0];
  const float* Wqkv  = (const float*)d_in[1];
  const float* bqkv  = (const float*)d_in[2];
  const float* Wo    = (const float*)d_in[3];
  const float* bo    = (const float*)d_in[4];
  const float* g1    = (const float*)d_in[5];
  const float* beta1 = (const float*)d_in[6];
  const float* W1    = (const float*)d_in[7];
  const float* bf1   = (const float*)d_in[8];
  const float* W2    = (const float*)d_in[9];
  const float* bf2   = (const float*)d_in[10];
  const float* g2    = (const float*)d_in[11];
  const float* beta2 = (const float*)d_in[12];
  float* out = (float*)d_out;

  unsigned short* ws = (unsigned short*)d_ws;
  unsigned short* WqkvT = ws;                          // 1536*512
  unsigned short* WoT   = ws + (size_t)1536 * 512;
  unsigned short* W1T   = WoT + (size_t)512 * 512;
  unsigned short* W2T   = W1T + (size_t)512 * 512;
  unsigned short* X     = W2T + (size_t)512 * 512;     // [2304][64][512] bf16

  transpose_cvt_kernel<<<dim3(48, 16), 256, 0, stream>>>(Wqkv, WqkvT, 512, 1536);
  transpose_cvt_kernel<<<dim3(16, 16), 256, 0, stream>>>(Wo, WoT, 512, 512);
  transpose_cvt_kernel<<<dim3(16, 16), 256, 0, stream>>>(W1, W1T, 512, 512);
  transpose_cvt_kernel<<<dim3(16, 16), 256, 0, stream>>>(W2, W2T, 512, 512);

  (void)hipFuncSetAttribute((const void*)swin_fused,
                            hipFuncAttributeMaxDynamicSharedMemorySize, SMEM_BYTES);
  swin_fused<<<NWIN, 512, SMEM_BYTES, stream>>>(x, WqkvT, bqkv, WoT, bo, g1, beta1,
                                                W1T, bf1, W2T, bf2, g2, beta2, X, out);
}

// Round 11
// 2660.458 us; speedup vs baseline: 1.6805x; 1.6805x over previous
//
#include <hip/hip_runtime.h>

typedef short short8 __attribute__((ext_vector_type(8)));
typedef float f32x4 __attribute__((ext_vector_type(4)));

#define NWIN 2304

static __device__ __forceinline__ unsigned short f2bf(float f) {
  unsigned int u = __float_as_uint(f);
  u += 0x7FFFu + ((u >> 16) & 1u);   // RNE
  return (unsigned short)(u >> 16);
}
static __device__ __forceinline__ float bf2f(unsigned short s) {
  return __uint_as_float(((unsigned int)s) << 16);
}
static __device__ __forceinline__ f32x4 mfma16(short8 a, short8 b, f32x4 c) {
  return __builtin_amdgcn_mfma_f32_16x16x32_bf16(a, b, c, 0, 0, 0);
}
static __device__ __forceinline__ short8 lds8(const unsigned short* p) {
  return *reinterpret_cast<const short8*>(p);
}
// XOR swizzles: 16B granule, spread by low row bits
static __device__ __forceinline__ int swzT(int r, int c) {   // [64][512]
  return r * 512 + ((((c >> 3) ^ (r & 7)) << 3) | (c & 7));
}
static __device__ __forceinline__ int swz128(int r, int c) { // [64][128]
  return r * 128 + ((((c >> 3) ^ (r & 7)) << 3) | (c & 7));
}
static __device__ __forceinline__ int swzV(int r, int c) {   // [128][64]
  return r * 64 + ((((c >> 3) ^ (r & 7)) << 3) | (c & 7));
}

// ---- weight prep: in[K][N] f32  ->  out[N][K] bf16 ----
__global__ void transpose_cvt_kernel(const float* __restrict__ in,
                                     unsigned short* __restrict__ out,
                                     int K, int N) {
  __shared__ float tile[32][33];
  int bn = blockIdx.x * 32, bk = blockIdx.y * 32;
  int tx = threadIdx.x & 31, ty = threadIdx.x >> 5;  // 256 thr: 32 x 8
#pragma unroll
  for (int r = 0; r < 32; r += 8)
    tile[ty + r][tx] = in[(size_t)(bk + ty + r) * N + bn + tx];
  __syncthreads();
#pragma unroll
  for (int r = 0; r < 32; r += 8)
    out[(size_t)(bn + ty + r) * K + bk + tx] = f2bf(tile[tx][ty + r]);
}

// ---- x prep: gather each window -> X[wid][64 tok][512 c] bf16 linear ----
__global__ __launch_bounds__(512) void prep_x_kernel(const float* __restrict__ x,
                                                     unsigned short* __restrict__ X) {
  extern __shared__ unsigned char smem[];
  unsigned short* s = (unsigned short*)smem;   // [64][512] linear
  const int tid = threadIdx.x;
  const int wid = (blockIdx.x & 7) * 288 + (blockIdx.x >> 3);
  const int b = wid / 144, rem = wid % 144;
  const int h0 = (rem / 12) * 8, w0 = (rem % 12) * 8;
  const float* xb = x + (size_t)b * 512 * 9216 + (size_t)h0 * 96 + w0;
  unsigned short* Xw = X + (size_t)wid * 32768;
#pragma unroll
  for (int it = 0; it < 16; ++it) {
    int gid = it * 512 + tid;                 // gid = c*16 + hr*2 + wq
    int c = gid >> 4, hr = (gid >> 1) & 7, wq = gid & 1;
    float4 v = *reinterpret_cast<const float4*>(xb + (size_t)c * 9216 + hr * 96 + wq * 4);
    int tok = hr * 8 + wq * 4;
    s[(tok + 0) * 512 + c] = f2bf(v.x);
    s[(tok + 1) * 512 + c] = f2bf(v.y);
    s[(tok + 2) * 512 + c] = f2bf(v.z);
    s[(tok + 3) * 512 + c] = f2bf(v.w);
  }
  __syncthreads();
#pragma unroll
  for (int it = 0; it < 8; ++it) {
    int gid = it * 512 + tid;                 // row*64 + granule
    int row = gid >> 6, c0 = (gid & 63) * 8;
    *reinterpret_cast<short8*>(Xw + row * 512 + c0) =
        *reinterpret_cast<const short8*>(s + row * 512 + c0);
  }
}

// ---- K1: attention (qkv + softmax + PV), O -> global ----
__global__ __launch_bounds__(512, 2)
void swin_attn(const unsigned short* __restrict__ X,
               const unsigned short* __restrict__ WqkvT,
               const float* __restrict__ bqkv,
               unsigned short* __restrict__ OWS) {
  extern __shared__ unsigned char smem[];
  unsigned short* sQ  = (unsigned short*)smem;             // [64][128] swz: q -> P
  unsigned short* sK  = (unsigned short*)(smem + 16384);   // [64][128] swz
  unsigned short* sVt = (unsigned short*)(smem + 32768);   // [128][64] swz

  const int tid = threadIdx.x;
  const int wvid = tid >> 6, lane = tid & 63;
  const int l16 = lane & 15, lg = lane >> 4;

  const int wid = (blockIdx.x & 7) * 288 + (blockIdx.x >> 3);
  const unsigned short* Xw = X + (size_t)wid * 32768;
  unsigned short* Ow = OWS + (size_t)wid * 32768;

  const int c2 = wvid * 16 + l16;   // qkv col within 128
  const int hh = wvid >> 2;         // head within pair
  const int mt4 = wvid & 3;         // 16-row tile

  for (int hp = 0; hp < 4; ++hp) {
    // ---- qkv in 3 lean passes (A from X via L2; acc[4] only) ----
#pragma unroll
    for (int pass = 0; pass < 3; ++pass) {
      const unsigned short* wp = WqkvT + ((size_t)pass * 512 + hp * 128 + c2) * 512;
      f32x4 acc[4] = {};
      short8 wb[2];
      wb[0] = *(const short8*)(wp + lg * 8);
      wb[1] = *(const short8*)(wp + 32 + lg * 8);
#pragma unroll
      for (int ks = 0; ks < 16; ++ks) {
        int ko = ks * 32 + lg * 8;
        short8 cw = wb[ks & 1];
        if (ks < 14) wb[ks & 1] = *(const short8*)(wp + (ks + 2) * 32 + lg * 8);
        short8 a0 = *(const short8*)(Xw + (l16) * 512 + ko);
        short8 a1 = *(const short8*)(Xw + (16 + l16) * 512 + ko);
        short8 a2 = *(const short8*)(Xw + (32 + l16) * 512 + ko);
        short8 a3 = *(const short8*)(Xw + (48 + l16) * 512 + ko);
        acc[0] = mfma16(a0, cw, acc[0]);
        acc[1] = mfma16(a1, cw, acc[1]);
        acc[2] = mfma16(a2, cw, acc[2]);
        acc[3] = mfma16(a3, cw, acc[3]);
      }
      float bv = bqkv[pass * 512 + hp * 128 + c2];
      if (pass == 0) {
#pragma unroll
        for (int mt = 0; mt < 4; ++mt) {
          int tok0 = mt * 16 + lg * 4;
#pragma unroll
          for (int r = 0; r < 4; ++r)
            sQ[swz128(tok0 + r, c2)] = f2bf((acc[mt][r] + bv) * 0.125f);
        }
      } else if (pass == 1) {
#pragma unroll
        for (int mt = 0; mt < 4; ++mt) {
          int tok0 = mt * 16 + lg * 4;
#pragma unroll
          for (int r = 0; r < 4; ++r)
            sK[swz128(tok0 + r, c2)] = f2bf(acc[mt][r] + bv);
        }
      } else {
#pragma unroll
        for (int mt = 0; mt < 4; ++mt) {
          int tok0 = mt * 16 + lg * 4;
          ushort4 pk;
          pk.x = f2bf(acc[mt][0] + bv);
          pk.y = f2bf(acc[mt][1] + bv);
          pk.z = f2bf(acc[mt][2] + bv);
          pk.w = f2bf(acc[mt][3] + bv);
          *reinterpret_cast<ushort4*>(sVt + swzV(c2, tok0)) = pk;
        }
      }
    }
    __syncthreads();

    // ---- scores + wave-local softmax (head hh, rows mt4*16..) ----
    {
      f32x4 sc[4] = {};
#pragma unroll
      for (int ks = 0; ks < 2; ++ks) {
        int kb = hh * 64 + ks * 32 + lg * 8;
        short8 a  = lds8(sQ + swz128(mt4 * 16 + l16, kb));
        short8 b0 = lds8(sK + swz128(l16, kb));
        short8 b1 = lds8(sK + swz128(16 + l16, kb));
        short8 b2 = lds8(sK + swz128(32 + l16, kb));
        short8 b3 = lds8(sK + swz128(48 + l16, kb));
        sc[0] = mfma16(a, b0, sc[0]);
        sc[1] = mfma16(a, b1, sc[1]);
        sc[2] = mfma16(a, b2, sc[2]);
        sc[3] = mfma16(a, b3, sc[3]);
      }
#pragma unroll
      for (int r = 0; r < 4; ++r) {
        float m = fmaxf(fmaxf(sc[0][r], sc[1][r]), fmaxf(sc[2][r], sc[3][r]));
        m = fmaxf(m, __shfl_xor(m, 1));
        m = fmaxf(m, __shfl_xor(m, 2));
        m = fmaxf(m, __shfl_xor(m, 4));
        m = fmaxf(m, __shfl_xor(m, 8));
        float e0 = __expf(sc[0][r] - m), e1 = __expf(sc[1][r] - m);
        float e2 = __expf(sc[2][r] - m), e3 = __expf(sc[3][r] - m);
        float s = e0 + e1 + e2 + e3;
        s += __shfl_xor(s, 1);
        s += __shfl_xor(s, 2);
        s += __shfl_xor(s, 4);
        s += __shfl_xor(s, 8);
        float inv = 1.0f / s;
        int row = mt4 * 16 + lg * 4 + r;
        sQ[swz128(row, hh * 64 + l16)]      = f2bf(e0 * inv);  // P over q (own rows)
        sQ[swz128(row, hh * 64 + 16 + l16)] = f2bf(e1 * inv);
        sQ[swz128(row, hh * 64 + 32 + l16)] = f2bf(e2 * inv);
        sQ[swz128(row, hh * 64 + 48 + l16)] = f2bf(e3 * inv);
      }
    }
    // no barrier: P produced and consumed by same wave

    // ---- PV: O = P @ V -> global OWS ----
    {
      f32x4 ov[4] = {};
#pragma unroll
      for (int ks = 0; ks < 2; ++ks) {
        int kb = ks * 32 + lg * 8;
        short8 a  = lds8(sQ + swz128(mt4 * 16 + l16, hh * 64 + kb));
        short8 b0 = lds8(sVt + swzV(hh * 64 + l16, kb));
        short8 b1 = lds8(sVt + swzV(hh * 64 + 16 + l16, kb));
        short8 b2 = lds8(sVt + swzV(hh * 64 + 32 + l16, kb));
        short8 b3 = lds8(sVt + swzV(hh * 64 + 48 + l16, kb));
        ov[0] = mfma16(a, b0, ov[0]);
        ov[1] = mfma16(a, b1, ov[1]);
        ov[2] = mfma16(a, b2, ov[2]);
        ov[3] = mfma16(a, b3, ov[3]);
      }
      int cb = hp * 128 + hh * 64;
#pragma unroll
      for (int r = 0; r < 4; ++r) {
        int row = mt4 * 16 + lg * 4 + r;
        Ow[row * 512 + cb + l16]      = f2bf(ov[0][r]);
        Ow[row * 512 + cb + 16 + l16] = f2bf(ov[1][r]);
        Ow[row * 512 + cb + 32 + l16] = f2bf(ov[2][r]);
        Ow[row * 512 + cb + 48 + l16] = f2bf(ov[3][r]);
      }
    }
    __syncthreads();  // next hp rewrites sQ/sK/sVt
  }
}

// ---- K2: o-proj + res/LN1 + FFN + res/LN2 -> out ----
__global__ __launch_bounds__(512, 2)
void swin_ffn(const float* __restrict__ x,
              const unsigned short* __restrict__ OWS,
              const unsigned short* __restrict__ WoT,
              const float* __restrict__ bo,
              const float* __restrict__ g1, const float* __restrict__ beta1,
              const unsigned short* __restrict__ W1T,
              const float* __restrict__ bf1,
              const unsigned short* __restrict__ W2T,
              const float* __restrict__ bf2,
              const float* __restrict__ g2, const float* __restrict__ beta2,
              float* __restrict__ out) {
  extern __shared__ unsigned char smem[];
  unsigned short* sBig = (unsigned short*)smem;            // [64][512] swz: x1
  unsigned short* sU   = (unsigned short*)(smem + 65536);  // [64][128] swz: hidden
  float* sSum  = (float*)(smem + 65536);                   // overlay sU (LN only)
  float* sSq   = (float*)(smem + 67584);
  float* sMean = (float*)(smem + 69632);
  float* sRstd = (float*)(smem + 69888);

  const int tid = threadIdx.x;
  const int wvid = tid >> 6, lane = tid & 63;
  const int l16 = lane & 15, lg = lane >> 4;

  const int wid = (blockIdx.x & 7) * 288 + (blockIdx.x >> 3);
  const int b = wid / 144, rem = wid % 144;
  const int h0 = (rem / 12) * 8, w0 = (rem % 12) * 8;
  const float* xb = x + (size_t)b * 512 * 9216 + (size_t)h0 * 96 + w0;
  float* ob = out + (size_t)b * 512 * 9216 + (size_t)h0 * 96 + w0;
  const unsigned short* Ow = OWS + (size_t)wid * 32768;

  const int c2 = wvid * 16 + l16;   // hidden col (F1)
  const int ycol0 = wvid * 64;      // wave's 64 C-cols (OP / LN / F2)

  // ---- OP: Y = O @ Wo (K=512; A from global O, L2-warm) ----
  f32x4 Yacc[4][4] = {};
  {
    const unsigned short* wo[4];
#pragma unroll
    for (int nt = 0; nt < 4; ++nt)
      wo[nt] = WoT + (size_t)(ycol0 + nt * 16 + l16) * 512;
    short8 wb[2][4];
#pragma unroll
    for (int p = 0; p < 2; ++p)
#pragma unroll
      for (int nt = 0; nt < 4; ++nt)
        wb[p][nt] = *(const short8*)(wo[nt] + p * 32 + lg * 8);
#pragma unroll
    for (int ks = 0; ks < 16; ++ks) {
      int ko = ks * 32 + lg * 8;
      short8 a0 = *(const short8*)(Ow + (l16) * 512 + ko);
      short8 a1 = *(const short8*)(Ow + (16 + l16) * 512 + ko);
      short8 a2 = *(const short8*)(Ow + (32 + l16) * 512 + ko);
      short8 a3 = *(const short8*)(Ow + (48 + l16) * 512 + ko);
#pragma unroll
      for (int nt = 0; nt < 4; ++nt) {
        short8 w = wb[ks & 1][nt];
        if (ks < 14) wb[ks & 1][nt] = *(const short8*)(wo[nt] + (ks + 2) * 32 + lg * 8);
        Yacc[0][nt] = mfma16(a0, w, Yacc[0][nt]);
        Yacc[1][nt] = mfma16(a1, w, Yacc[1][nt]);
        Yacc[2][nt] = mfma16(a2, w, Yacc[2][nt]);
        Yacc[3][nt] = mfma16(a3, w, Yacc[3][nt]);
      }
    }
  }

  // ---- Residual 1 (x from global) + LayerNorm 1 -> x1 in sBig ----
  {
#pragma unroll
    for (int nt = 0; nt < 4; ++nt) {
      int col = ycol0 + nt * 16 + l16;
      float bv = bo[col];
      const float* xc = xb + (size_t)col * 9216;
#pragma unroll
      for (int mt = 0; mt < 4; ++mt) {
        int row0 = mt * 16 + lg * 4;
        float4 xv = *reinterpret_cast<const float4*>(xc + (row0 >> 3) * 96 + (row0 & 7));
        Yacc[mt][nt][0] += bv + xv.x;
        Yacc[mt][nt][1] += bv + xv.y;
        Yacc[mt][nt][2] += bv + xv.z;
        Yacc[mt][nt][3] += bv + xv.w;
      }
    }
#pragma unroll
    for (int mt = 0; mt < 4; ++mt) {
#pragma unroll
      for (int r = 0; r < 4; ++r) {
        float s = Yacc[mt][0][r] + Yacc[mt][1][r] + Yacc[mt][2][r] + Yacc[mt][3][r];
        float q = Yacc[mt][0][r] * Yacc[mt][0][r] + Yacc[mt][1][r] * Yacc[mt][1][r] +
                  Yacc[mt][2][r] * Yacc[mt][2][r] + Yacc[mt][3][r] * Yacc[mt][3][r];
        s += __shfl_xor(s, 1); s += __shfl_xor(s, 2);
        s += __shfl_xor(s, 4); s += __shfl_xor(s, 8);
        q += __shfl_xor(q, 1); q += __shfl_xor(q, 2);
        q += __shfl_xor(q, 4); q += __shfl_xor(q, 8);
        if (l16 == 0) {
          sSum[wvid * 64 + mt * 16 + lg * 4 + r] = s;
          sSq[wvid * 64 + mt * 16 + lg * 4 + r] = q;
        }
      }
    }
    __syncthreads();
    if (tid < 64) {
      float s = 0.f, q = 0.f;
#pragma unroll
      for (int w = 0; w < 8; ++w) { s += sSum[w * 64 + tid]; q += sSq[w * 64 + tid]; }
      float mean = s * (1.0f / 512.0f);
      float var = q * (1.0f / 512.0f) - mean * mean;
      sMean[tid] = mean;
      sRstd[tid] = rsqrtf(var + 1e-5f);
    }
    __syncthreads();
#pragma unroll
    for (int nt = 0; nt < 4; ++nt) {
      int col = ycol0 + nt * 16 + l16;
      float gv = g1[col], bv = beta1[col];
#pragma unroll
      for (int mt = 0; mt < 4; ++mt) {
        int row0 = mt * 16 + lg * 4;
#pragma unroll
        for (int r = 0; r < 4; ++r) {
          float xv = (Yacc[mt][nt][r] - sMean[row0 + r]) * sRstd[row0 + r] * gv + bv;
          sBig[swzT(row0 + r, col)] = f2bf(xv);
        }
      }
    }
  }
  __syncthreads();

  // ---- FFN: 4 hidden chunks of 128 ----
  f32x4 Facc[4][4] = {};
  for (int hc = 0; hc < 4; ++hc) {
    // F1: u = relu(x1 @ W1 chunk)
    {
      const int hcol = hc * 128 + c2;
      const unsigned short* w1p = W1T + (size_t)hcol * 512;
      f32x4 u[4] = {};
      short8 wbuf[2];
      wbuf[0] = *(const short8*)(w1p + lg * 8);
      wbuf[1] = *(const short8*)(w1p + 32 + lg * 8);
#pragma unroll
      for (int ks = 0; ks < 16; ++ks) {
        int ko = ks * 32 + lg * 8;
        short8 cw = wbuf[ks & 1];
        if (ks < 14)
          wbuf[ks & 1] = *(const short8*)(w1p + (ks + 2) * 32 + lg * 8);
        short8 a0 = lds8(sBig + swzT(l16, ko));
        short8 a1 = lds8(sBig + swzT(16 + l16, ko));
        short8 a2 = lds8(sBig + swzT(32 + l16, ko));
        short8 a3 = lds8(sBig + swzT(48 + l16, ko));
        u[0] = mfma16(a0, cw, u[0]);
        u[1] = mfma16(a1, cw, u[1]);
        u[2] = mfma16(a2, cw, u[2]);
        u[3] = mfma16(a3, cw, u[3]);
      }
      float bv = bf1[hcol];
#pragma unroll
      for (int mt = 0; mt < 4; ++mt) {
        int tok0 = mt * 16 + lg * 4;
#pragma unroll
        for (int r = 0; r < 4; ++r)
          sU[swz128(tok0 + r, c2)] = f2bf(fmaxf(u[mt][r] + bv, 0.0f));
      }
    }
    __syncthreads();
    // F2: Facc += u @ W2[hc*128.., ycol0..+64]
    {
      const unsigned short* w2[4];
#pragma unroll
      for (int nt = 0; nt < 4; ++nt)
        w2[nt] = W2T + (size_t)(ycol0 + nt * 16 + l16) * 512 + hc * 128;
#pragma unroll
      for (int ks = 0; ks < 4; ++ks) {
        int ko = ks * 32 + lg * 8;
        short8 a0 = lds8(sU + swz128(l16, ko));
        short8 a1 = lds8(sU + swz128(16 + l16, ko));
        short8 a2 = lds8(sU + swz128(32 + l16, ko));
        short8 a3 = lds8(sU + swz128(48 + l16, ko));
#pragma unroll
        for (int nt = 0; nt < 4; ++nt) {
          short8 w = *(const short8*)(w2[nt] + ko);
          Facc[0][nt] = mfma16(a0, w, Facc[0][nt]);
          Facc[1][nt] = mfma16(a1, w, Facc[1][nt]);
          Facc[2][nt] = mfma16(a2, w, Facc[2][nt]);
          Facc[3][nt] = mfma16(a3, w, Facc[3][nt]);
        }
      }
    }
    __syncthreads();  // sU reused next chunk
  }

  // ---- Residual 2 (x1 from sBig) + LayerNorm 2 -> output ----
  {
#pragma unroll
    for (int nt = 0; nt < 4; ++nt) {
      int col = ycol0 + nt * 16 + l16;
      float bv = bf2[col];
#pragma unroll
      for (int mt = 0; mt < 4; ++mt) {
        int row0 = mt * 16 + lg * 4;
#pragma unroll
        for (int r = 0; r < 4; ++r)
          Facc[mt][nt][r] += bv + bf2f(sBig[swzT(row0 + r, col)]);
      }
    }
#pragma unroll
    for (int mt = 0; mt < 4; ++mt) {
#pragma unroll
      for (int r = 0; r < 4; ++r) {
        float s = Facc[mt][0][r] + Facc[mt][1][r] + Facc[mt][2][r] + Facc[mt][3][r];
        float q = Facc[mt][0][r] * Facc[mt][0][r] + Facc[mt][1][r] * Facc[mt][1][r] +
                  Facc[mt][2][r] * Facc[mt][2][r] + Facc[mt][3][r] * Facc[mt][3][r];
        s += __shfl_xor(s, 1); s += __shfl_xor(s, 2);
        s += __shfl_xor(s, 4); s += __shfl_xor(s, 8);
        q += __shfl_xor(q, 1); q += __shfl_xor(q, 2);
        q += __shfl_xor(q, 4); q += __shfl_xor(q, 8);
        if (l16 == 0) {
          sSum[wvid * 64 + mt * 16 + lg * 4 + r] = s;
          sSq[wvid * 64 + mt * 16 + lg * 4 + r] = q;
        }
      }
    }
    __syncthreads();
    if (tid < 64) {
      float s = 0.f, q = 0.f;
#pragma unroll
      for (int w = 0; w < 8; ++w) { s += sSum[w * 64 + tid]; q += sSq[w * 64 + tid]; }
      float mean = s * (1.0f / 512.0f);
      float var = q * (1.0f / 512.0f) - mean * mean;
      sMean[tid] = mean;
      sRstd[tid] = rsqrtf(var + 1e-5f);
    }
    __syncthreads();
#pragma unroll
    for (int nt = 0; nt < 4; ++nt) {
      int col = ycol0 + nt * 16 + l16;
      float gv = g2[col], bv = beta2[col];
      float* op = ob + (size_t)col * 9216;
#pragma unroll
      for (int mt = 0; mt < 4; ++mt) {
        int t0 = mt * 16 + lg * 4;
        float4 o4;
        o4.x = (Facc[mt][nt][0] - sMean[t0 + 0]) * sRstd[t0 + 0] * gv + bv;
        o4.y = (Facc[mt][nt][1] - sMean[t0 + 1]) * sRstd[t0 + 1] * gv + bv;
        o4.z = (Facc[mt][nt][2] - sMean[t0 + 2]) * sRstd[t0 + 2] * gv + bv;
        o4.w = (Facc[mt][nt][3] - sMean[t0 + 3]) * sRstd[t0 + 3] * gv + bv;
        *reinterpret_cast<float4*>(op + (t0 >> 3) * 96 + (t0 & 7)) = o4;
      }
    }
  }
}

extern "C" void kernel_launch(void* const* d_in, const int* in_sizes, int n_in,
                              void* d_out, int out_size, void* d_ws, size_t ws_size,
                              hipStream_t stream) {
  const float* x     = (const float*)d_in[0];
  const float* Wqkv  = (const float*)d_in[1];
  const float* bqkv  = (const float*)d_in[2];
  const float* Wo    = (const float*)d_in[3];
  const float* bo    = (const float*)d_in[4];
  const float* g1    = (const float*)d_in[5];
  const float* beta1 = (const float*)d_in[6];
  const float* W1    = (const float*)d_in[7];
  const float* bf1   = (const float*)d_in[8];
  const float* W2    = (const float*)d_in[9];
  const float* bf2   = (const float*)d_in[10];
  const float* g2    = (const float*)d_in[11];
  const float* beta2 = (const float*)d_in[12];
  float* out = (float*)d_out;

  unsigned short* ws = (unsigned short*)d_ws;
  unsigned short* WqkvT = ws;                          // 1536*512
  unsigned short* WoT   = ws + (size_t)1536 * 512;
  unsigned short* W1T   = WoT + (size_t)512 * 512;
  unsigned short* W2T   = W1T + (size_t)512 * 512;
  unsigned short* X     = W2T + (size_t)512 * 512;     // [2304][64][512] bf16
  unsigned short* OWS   = X + (size_t)NWIN * 32768;    // [2304][64][512] bf16

  transpose_cvt_kernel<<<dim3(48, 16), 256, 0, stream>>>(Wqkv, WqkvT, 512, 1536);
  transpose_cvt_kernel<<<dim3(16, 16), 256, 0, stream>>>(Wo, WoT, 512, 512);
  transpose_cvt_kernel<<<dim3(16, 16), 256, 0, stream>>>(W1, W1T, 512, 512);
  transpose_cvt_kernel<<<dim3(16, 16), 256, 0, stream>>>(W2, W2T, 512, 512);

  (void)hipFuncSetAttribute((const void*)prep_x_kernel,
                            hipFuncAttributeMaxDynamicSharedMemorySize, 65536);
  (void)hipFuncSetAttribute((const void*)swin_attn,
                            hipFuncAttributeMaxDynamicSharedMemorySize, 49152);
  (void)hipFuncSetAttribute((const void*)swin_ffn,
                            hipFuncAttributeMaxDynamicSharedMemorySize, 81920);

  prep_x_kernel<<<NWIN, 512, 65536, stream>>>(x, X);
  swin_attn<<<NWIN, 512, 49152, stream>>>(X, WqkvT, bqkv, OWS);
  swin_ffn<<<NWIN, 512, 81920, stream>>>(x, OWS, WoT, bo, g1, beta1,
                                         W1T, bf1, W2T, bf2, g2, beta2, out);
}